// Round 4
// baseline (260.802 us; speedup 1.0000x reference)
//
#include <hip/hip_runtime.h>
#include <math.h>

#define T_FRAMES 16384
#define FDIM 2048
#define LQ 30
#define F_BLK 8       // frames per block (feas kernel)
#define BF 64         // frames per block (attn kernel)

// ---------------------------------------------------------------------------
// Kernel 0: precompute per-head 7x7 bilinear forms
//   A_h[c][c2] = sum_d W_q[h*64+d][c] * W_k[h*64+d][c2]
//   M_h[c][c2] = sum_d W_o[c][h*64+d] * W_v[h*64+d][c2]
// AM layout: [0..195] = A (h*49 + c*7 + c2), [196..391] = M
// ---------------------------------------------------------------------------
__global__ __launch_bounds__(448) void setup_kernel(
    const float* __restrict__ Wq, const float* __restrict__ Wk,
    const float* __restrict__ Wv, const float* __restrict__ Wo,
    float* __restrict__ AM) {
  const int e = threadIdx.x;
  if (e >= 392) return;
  const int which = e / 196;
  const int r = e % 196;
  const int h = r / 49;
  const int rr = r % 49;
  const int c = rr / 7;
  const int c2 = rr % 7;
  float s = 0.0f;
  if (which == 0) {
    for (int d = 0; d < 64; ++d)
      s = fmaf(Wq[(h * 64 + d) * 7 + c], Wk[(h * 64 + d) * 7 + c2], s);
  } else {
    for (int d = 0; d < 64; ++d)
      s = fmaf(Wo[c * 256 + h * 64 + d], Wv[(h * 64 + d) * 7 + c2], s);
  }
  AM[e] = s;
}

// ---------------------------------------------------------------------------
// Kernel 1 (v5): feas[t][c] = tanh(lf[t] . Wfc[c])
// SEQUENTIAL-DRAM design: each block stages a CONTIGUOUS 64 KB lf slice
// (8 frames) through LDS with coalesced float4 bursts -- the chip-wide
// address stream is ~512 sequential 64 KB windows instead of 4096 scattered
// 1 KB-granule row-walks (the suspected DRAM row-thrash limiter of v1-v4).
// Compute is column-sliced: wave w owns columns [256w,256w+256); each lane
// keeps its 7 x float4 Wfc slice IN REGISTERS (no Wfc re-reads at all).
// Per frame: 1 ds_read_b128 + 28 FMA; butterfly allreduce; cross-wave sum
// via tiny LDS buffer.
// ---------------------------------------------------------------------------
__global__ __launch_bounds__(512, 4) void feas_kernel(
    const float* __restrict__ lf,    // (T, 2048)
    const float* __restrict__ Wfc,   // (7, 2048)
    float* __restrict__ feas) {      // (T, 7)
  __shared__ float lfs[F_BLK * FDIM];   // 64 KB
  __shared__ float red[8][56];          // cross-wave partials

  const int tid = threadIdx.x;
  const int lane = tid & 63;
  const int wave = tid >> 6;            // 0..7
  const size_t base = (size_t)blockIdx.x * (F_BLK * FDIM);

  // Wfc slice -> registers (lane covers columns col..col+3, fixed)
  const int col = wave * 256 + lane * 4;
  float4 w[7];
#pragma unroll
  for (int c = 0; c < 7; ++c) w[c] = *(const float4*)(Wfc + c * FDIM + col);

  // stage 64 KB contiguous: 8 rounds, thread t -> floats r*2048 + t*4
  float4 st[8];
#pragma unroll
  for (int r = 0; r < 8; ++r)
    st[r] = *(const float4*)(lf + base + r * 2048 + tid * 4);
#pragma unroll
  for (int r = 0; r < 8; ++r)
    *(float4*)(&lfs[r * 2048 + tid * 4]) = st[r];
  __syncthreads();

  // per-frame partial dot over this lane's 4 columns
  float acc[F_BLK][7];
#pragma unroll
  for (int f = 0; f < F_BLK; ++f) {
    const float4 a = *(const float4*)(&lfs[f * FDIM + col]);
#pragma unroll
    for (int c = 0; c < 7; ++c)
      acc[f][c] = fmaf(a.x, w[c].x, fmaf(a.y, w[c].y,
                  fmaf(a.z, w[c].z, a.w * w[c].w)));
  }

  // butterfly allreduce across the 64 lanes (wave covers 256 columns)
#pragma unroll
  for (int f = 0; f < F_BLK; ++f)
#pragma unroll
    for (int c = 0; c < 7; ++c)
#pragma unroll
      for (int off = 1; off < 64; off <<= 1)
        acc[f][c] += __shfl_xor(acc[f][c], off, 64);

  // lane i < 56 publishes acc[i/7][i%7] (static select chain -> stays in regs)
  if (lane < 56) {
    float v = acc[0][0];
#pragma unroll
    for (int f = 0; f < F_BLK; ++f)
#pragma unroll
      for (int c = 0; c < 7; ++c)
        if (lane == f * 7 + c) v = acc[f][c];
    red[wave][lane] = v;
  }
  __syncthreads();

  // cross-wave sum (8 partials) + tanh + contiguous store
  if (tid < 56) {
    float s = 0.0f;
#pragma unroll
    for (int wv = 0; wv < 8; ++wv) s += red[wv][tid];
    feas[(size_t)blockIdx.x * (F_BLK * 7) + tid] = tanhf(s);
  }
}

// ---------------------------------------------------------------------------
// Kernel 2: attention + FFN + LNs (unchanged -- verified, cheap).
// 64 frames/block; 2a uses all 256 threads; reads feas from `out`,
// overwrites in place (LDS-staged before the barrier).
// ---------------------------------------------------------------------------
__global__ __launch_bounds__(256) void attn_kernel(
    const float* __restrict__ x,       // (7, T)
    const float* __restrict__ feas_g,  // (T, 7)  == out
    const float* __restrict__ AM,      // 392
    const float* __restrict__ W1,      // (64, 7)
    const float* __restrict__ W2,      // (7, 64)
    const float* __restrict__ ln1g, const float* __restrict__ ln1b,
    const float* __restrict__ ln2g, const float* __restrict__ ln2b,
    float* __restrict__ out) {         // (T, 7)
  __shared__ float AM_s[392];
  __shared__ float ft[(BF + LQ - 1) * 7];
  __shared__ float feas_s[BF][7];
  __shared__ float hpart[BF][4][7];

  const int tid = threadIdx.x;
  const int t0 = blockIdx.x * BF;

  for (int i = tid; i < 392; i += 256) AM_s[i] = AM[i];
  for (int i = tid; i < (BF + LQ - 1) * 7; i += 256) {
    const int row = i / 7, c = i % 7;
    const int s = t0 - (LQ - 1) + row;
    ft[i] = (s >= 0) ? x[c * T_FRAMES + s] : 0.0f;
  }
  for (int i = tid; i < BF * 7; i += 256)
    feas_s[i / 7][i % 7] = feas_g[(size_t)t0 * 7 + i];
  __syncthreads();

  // ---- phase 2a: (frame, head) per thread, 256/256 active ----
  {
    const int f = tid >> 2;
    const int h = tid & 3;
    float fe[7];
#pragma unroll
    for (int c = 0; c < 7; ++c) fe[c] = feas_s[f][c];

    const float* Ah = AM_s + h * 49;
    const float* Mh = AM_s + 196 + h * 49;
    float qk[7];
#pragma unroll
    for (int c2 = 0; c2 < 7; ++c2) {
      float s = 0.0f;
#pragma unroll
      for (int c = 0; c < 7; ++c) s = fmaf(fe[c], Ah[c * 7 + c2], s);
      qk[c2] = s * 0.125f;
    }
    const float* frow = &ft[f * 7];
    float sc[LQ];
    float m = -1e30f;
#pragma unroll
    for (int j = 0; j < LQ; ++j) {
      const float* r = frow + j * 7;
      float s = 0.0f;
#pragma unroll
      for (int c2 = 0; c2 < 7; ++c2) s = fmaf(qk[c2], r[c2], s);
      sc[j] = s;
      m = fmaxf(m, s);
    }
    float sum = 0.0f;
    float wsum[7] = {0, 0, 0, 0, 0, 0, 0};
#pragma unroll
    for (int j = 0; j < LQ; ++j) {
      const float p = __expf(sc[j] - m);
      sum += p;
      const float* r = frow + j * 7;
#pragma unroll
      for (int c2 = 0; c2 < 7; ++c2) wsum[c2] = fmaf(p, r[c2], wsum[c2]);
    }
    const float inv = 1.0f / sum;
#pragma unroll
    for (int c = 0; c < 7; ++c) {
      float s = 0.0f;
#pragma unroll
      for (int c2 = 0; c2 < 7; ++c2) s = fmaf(Mh[c * 7 + c2], wsum[c2], s);
      hpart[f][h][c] = s * inv;
    }
  }
  __syncthreads();

  // ---- phase 2b: per-frame epilogue ----
  if (tid < BF) {
    const int f = tid;
    float v[7];
#pragma unroll
    for (int c = 0; c < 7; ++c)
      v[c] = feas_s[f][c] + hpart[f][0][c] + hpart[f][1][c] + hpart[f][2][c] + hpart[f][3][c];

    float mu = 0.0f;
#pragma unroll
    for (int c = 0; c < 7; ++c) mu += v[c];
    mu *= (1.0f / 7.0f);
    float var = 0.0f;
#pragma unroll
    for (int c = 0; c < 7; ++c) { const float d = v[c] - mu; var = fmaf(d, d, var); }
    var *= (1.0f / 7.0f);
    float rs = rsqrtf(var + 1e-5f);
    float o1[7];
#pragma unroll
    for (int c = 0; c < 7; ++c) o1[c] = (v[c] - mu) * rs * ln1g[c] + ln1b[c];

    float ff[7] = {0, 0, 0, 0, 0, 0, 0};
    for (int k = 0; k < 64; ++k) {
      float hk = 0.0f;
#pragma unroll
      for (int c = 0; c < 7; ++c) hk = fmaf(W1[k * 7 + c], o1[c], hk);
      hk = fmaxf(hk, 0.0f);
#pragma unroll
      for (int c = 0; c < 7; ++c) ff[c] = fmaf(W2[c * 64 + k], hk, ff[c]);
    }

#pragma unroll
    for (int c = 0; c < 7; ++c) v[c] = ff[c] + o1[c];
    mu = 0.0f;
#pragma unroll
    for (int c = 0; c < 7; ++c) mu += v[c];
    mu *= (1.0f / 7.0f);
    var = 0.0f;
#pragma unroll
    for (int c = 0; c < 7; ++c) { const float d = v[c] - mu; var = fmaf(d, d, var); }
    var *= (1.0f / 7.0f);
    rs = rsqrtf(var + 1e-5f);
    const int t = t0 + f;
#pragma unroll
    for (int c = 0; c < 7; ++c)
      out[(size_t)t * 7 + c] = (v[c] - mu) * rs * ln2g[c] + ln2b[c];
  }
}

// ---------------------------------------------------------------------------
extern "C" void kernel_launch(void* const* d_in, const int* in_sizes, int n_in,
                              void* d_out, int out_size, void* d_ws, size_t ws_size,
                              hipStream_t stream) {
  const float* x    = (const float*)d_in[0];   // (1, 7, T)
  const float* lf   = (const float*)d_in[1];   // (1, T, 2048)
  const float* Wfc  = (const float*)d_in[2];   // (7, 2048)
  const float* Wq   = (const float*)d_in[3];   // (256, 7)
  const float* Wk   = (const float*)d_in[4];   // (256, 7)
  const float* Wv   = (const float*)d_in[5];   // (256, 7)
  const float* Wo   = (const float*)d_in[6];   // (7, 256)
  const float* ln1g = (const float*)d_in[7];
  const float* ln1b = (const float*)d_in[8];
  const float* W1   = (const float*)d_in[9];   // (64, 7)
  const float* W2   = (const float*)d_in[10];  // (7, 64)
  const float* ln2g = (const float*)d_in[11];
  const float* ln2b = (const float*)d_in[12];
  float* out = (float*)d_out;

  float* AM = (float*)d_ws;   // 392 floats

  setup_kernel<<<1, 448, 0, stream>>>(Wq, Wk, Wv, Wo, AM);
  // feas written into `out` (scratch); attn_kernel rewrites it in place.
  feas_kernel<<<T_FRAMES / F_BLK, 512, 0, stream>>>(lf, Wfc, out);
  attn_kernel<<<T_FRAMES / BF, 256, 0, stream>>>(
      x, out, AM, W1, W2, ln1g, ln1b, ln2g, ln2b, out);
}